// Round 2
// baseline (432.864 us; speedup 1.0000x reference)
//
#include <hip/hip_runtime.h>
#include <hip/hip_bf16.h>
#include <math.h>

// B=4096, S=200, D=64, H=36
#define BB 4096
#define SS 200
#define DD 64
#define HH 36
#define NP 48            // H padded to 3 n-tiles of 16
#define NROWSF (4096.0f * 200.0f)
#define NPB (2 * BB)     // 8192 blocks: (b, half)
#define PSTRIDE 80       // per-block partial-stat row stride (dwords)

typedef short bf16x8 __attribute__((ext_vector_type(8)));
typedef float f32x4 __attribute__((ext_vector_type(4)));

__device__ __forceinline__ unsigned short f2bf(float f) {
    union { float f; unsigned u; } v; v.f = f;
    unsigned r = v.u + 0x7FFFu + ((v.u >> 16) & 1u);   // RNE
    return (unsigned short)(r >> 16);
}
__device__ __forceinline__ unsigned f2bf2(float a, float b) {
    union { __hip_bfloat162 h; unsigned u; } v;
    v.h = __float22bfloat162_rn(float2{a, b});         // packed cvt on gfx950
    return v.u;
}

// Fire-and-forget global->LDS DMA, 16B per lane. LDS dest must be linear:
// wave-uniform base + lane*16 (m104); we pass per-lane ptrs laid out exactly so.
__device__ __forceinline__ void gl_lds16(const void* g, void* l) {
    __builtin_amdgcn_global_load_lds(
        (const __attribute__((address_space(1))) unsigned*)g,
        (__attribute__((address_space(3))) unsigned*)l, 16, 0, 0);
}

// ---------------------------------------------------------------------------
// k_wb: per-b folded weights/bias, computed ONCE.
// WbG[b][n][k] bf16 (n<36 real, else 0); baseG[b][0..47].
//   Wb[k][n] = W1b[k][n] - W1c[k][n] + c[k]*W1d[k][n]
//   base[n]  = b1[n] + sum_k c[k]*(W1a[k][n] + W1c[k][n])
// ---------------------------------------------------------------------------
__global__ __launch_bounds__(256) void k_wb(const float* __restrict__ cand,
                                            const float* __restrict__ W1,
                                            const float* __restrict__ b1,
                                            unsigned short* __restrict__ WbG,
                                            float* __restrict__ baseG) {
    int b = blockIdx.x, t = threadIdx.x;
    __shared__ float shC[DD];
    if (t < DD) shC[t] = cand[b * DD + t];
    __syncthreads();
    unsigned short* wb = WbG + (size_t)b * (NP * DD);
#pragma unroll
    for (int u = 0; u < 12; ++u) {              // 48*64/256
        int e = t + u * 256;
        int n = e >> 6, k = e & 63;
        float val = 0.f;
        if (n < HH)
            val = W1[(DD + k) * HH + n] - W1[(2 * DD + k) * HH + n] +
                  shC[k] * W1[(3 * DD + k) * HH + n];
        wb[e] = f2bf(val);
    }
    if (t < NP) {
        float v = 0.f;
        if (t < HH) {
            v = b1[t];
            for (int k = 0; k < DD; ++k)
                v += shC[k] * (W1[k * HH + t] + W1[(2 * DD + k) * HH + t]);
        }
        baseG[b * NP + t] = v;
    }
}

// ---------------------------------------------------------------------------
// Prologue: stage half of hist (fp32, LINEAR) + WbT (bf16, LINEAR) + base.
// WB=true: global_load_lds DMA, zero staging VGPRs, 1 barrier.
// WB=false: register-staged fallback (rebuild Wb from W1 in-block).
// half0: local rows 0-111 (tiles 0-6); half1: rows 112-199 + 8 zero pad rows.
// ---------------------------------------------------------------------------
template <bool WB>
__device__ __forceinline__ void prologue(int b, int half, int t,
                                         const float* __restrict__ hist,
                                         const float* __restrict__ cand,
                                         const float* __restrict__ W1,
                                         const float* __restrict__ b1,
                                         const unsigned short* __restrict__ WbG,
                                         const float* __restrict__ baseG,
                                         float* shHf, unsigned short* shWbT,
                                         float* shC, float* shBase,
                                         float (*shBaseP)[NP]) {
    int w = t >> 6, l = t & 63;
    const float* hsrc = hist + ((size_t)b * SS + (half ? 112 : 0)) * DD;
    if (WB) {
        const char* hb = (const char*)hsrc;
        char* lb = (char*)shHf;
        // hist: half0 = 28672B (28x1KB), half1 = 22528B (22x1KB), contiguous
#pragma unroll
        for (int u = 0; u < 7; ++u) {
            int j = w * 7 + u;
            if (!half || j < 22)
                gl_lds16(hb + j * 1024 + l * 16, lb + j * 1024 + l * 16);
        }
        // WbT: 48x64 bf16 = 6144B contiguous
        const char* wbsrc = (const char*)(WbG + (size_t)b * (NP * DD));
        char* wbl = (char*)shWbT;
        gl_lds16(wbsrc + w * 1024 + l * 16, wbl + w * 1024 + l * 16);
        if (w < 2)
            gl_lds16(wbsrc + (4 + w) * 1024 + l * 16, wbl + (4 + w) * 1024 + l * 16);
        if (t < NP) shBase[t] = baseG[b * NP + t];
        if (half && t < 128)                 // zero pad rows 88..95
            *(float4*)&shHf[88 * DD + t * 4] = float4{0.f, 0.f, 0.f, 0.f};
        __syncthreads();                     // drains vmcnt (incl. DMA) + lgkm
    } else {
        if (t < DD) shC[t] = cand[b * DD + t];
        const float4* src = (const float4*)hsrc;
        float4 v[7];
        if (!half) {
#pragma unroll
            for (int u = 0; u < 7; ++u) v[u] = src[t + u * 256];
        } else {
#pragma unroll
            for (int u = 0; u < 5; ++u) v[u] = src[t + u * 256];
            if (t < 128) v[5] = src[t + 1280];
            if (t < 128) *(float4*)&shHf[88 * DD + t * 4] = float4{0.f, 0.f, 0.f, 0.f};
        }
        __syncthreads();                     // shC visible
#pragma unroll
        for (int u = 0; u < 7; ++u) {
            int i = t + u * 256;
            bool act = half ? (u < 5 || (u == 5 && t < 128)) : true;
            if (u < 6 || !half) {
                if (act) *(float4*)&shHf[i * 4] = v[u];
            }
        }
        for (int e = t; e < NP * DD; e += 256) {
            int n = e >> 6, k = e & 63;
            float val = 0.f;
            if (n < HH)
                val = W1[(DD + k) * HH + n] - W1[(2 * DD + k) * HH + n] +
                      shC[k] * W1[(3 * DD + k) * HH + n];
            shWbT[n * DD + k] = f2bf(val);
        }
        if (t < 4 * NP) {
            int g = t / NP, j = t - g * NP;
            float p = 0.f;
            if (j < HH) {
#pragma unroll 4
                for (int k = 16 * g; k < 16 * g + 16; ++k)
                    p += shC[k] * (W1[k * HH + j] + W1[(2 * DD + k) * HH + j]);
            }
            shBaseP[g][j] = p;
        }
        __syncthreads();
        if (t < NP) {
            float val = (t < HH) ? b1[t] : 0.f;
            shBase[t] = val + shBaseP[0][t] + shBaseP[1][t] + shBaseP[2][t] +
                        shBaseP[3][t];
        }
        __syncthreads();
    }
}

__device__ __forceinline__ void load_bfrags(const unsigned short* shWbT, int lane,
                                            bf16x8 (&bfr)[3][2]) {
    int col = lane & 15, q = lane >> 4;
#pragma unroll
    for (int nt = 0; nt < 3; ++nt)
#pragma unroll
        for (int kt = 0; kt < 2; ++kt)
            bfr[nt][kt] = *(const bf16x8*)&shWbT[(nt * 16 + col) * DD + kt * 32 + q * 8];
}

// A-fragment: read 8 fp32 from linear LDS, pack to bf16 (same RNE as before)
__device__ __forceinline__ bf16x8 load_afrag(const float* shHf, int m, int kt, int q) {
    const float* rp = shHf + m * DD + kt * 32 + q * 8;
    f32x4 x0 = *(const f32x4*)rp;
    f32x4 x1 = *(const f32x4*)(rp + 4);
    union { bf16x8 b8; unsigned u[4]; } a;
    a.u[0] = f2bf2(x0[0], x0[1]);
    a.u[1] = f2bf2(x0[2], x0[3]);
    a.u[2] = f2bf2(x1[0], x1[1]);
    a.u[3] = f2bf2(x1[2], x1[3]);
    return a.b8;
}

__device__ __forceinline__ void gemm_tile(const float* shHf,
                                          const bf16x8 (&bfr)[3][2], int mt, int lane,
                                          f32x4 (&d)[3]) {
    int m = mt * 16 + (lane & 15), q = lane >> 4;
    d[0] = f32x4{0.f, 0.f, 0.f, 0.f};
    d[1] = f32x4{0.f, 0.f, 0.f, 0.f};
    d[2] = f32x4{0.f, 0.f, 0.f, 0.f};
#pragma unroll
    for (int kt = 0; kt < 2; ++kt) {
        bf16x8 a = load_afrag(shHf, m, kt, q);
#pragma unroll
        for (int nt = 0; nt < 3; ++nt)
            d[nt] = __builtin_amdgcn_mfma_f32_16x16x32_bf16(a, bfr[nt][kt], d[nt], 0, 0, 0);
    }
}

// ---------------------------------------------------------------------------
// Pass 1: column sums of h and h^2 (BN batch statistics)
// ---------------------------------------------------------------------------
template <bool WB, bool RED>
__global__ __launch_bounds__(256, 4) void k_pass1(const float* __restrict__ hist,
                                                  const float* __restrict__ cand,
                                                  const float* __restrict__ W1,
                                                  const float* __restrict__ b1,
                                                  const unsigned short* __restrict__ WbG,
                                                  const float* __restrict__ baseG,
                                                  float* __restrict__ pstat,
                                                  float* __restrict__ gsum,
                                                  float* __restrict__ gsum2) {
    __shared__ __align__(16) float shHf[112 * DD];
    __shared__ __align__(16) unsigned short shWbT[NP * DD];
    __shared__ float shC[WB ? 1 : DD], shBase[NP];
    __shared__ float shBaseP[WB ? 1 : 4][NP];
    __shared__ float shP1[4][NP], shP2[4][NP];
    int bx = blockIdx.x, b = bx >> 1, half = bx & 1;
    int t = threadIdx.x, wave = t >> 6, lane = t & 63;
    int col = lane & 15, q = lane >> 4;

    prologue<WB>(b, half, t, hist, cand, W1, b1, WbG, baseG, shHf, shWbT, shC,
                 shBase, shBaseP);

    bf16x8 bfr[3][2];
    load_bfrags(shWbT, lane, bfr);
    float basev[3];
#pragma unroll
    for (int nt = 0; nt < 3; ++nt) basev[nt] = shBase[nt * 16 + col];

    const int NTl = half ? 6 : 7;
    float cs1[3] = {0.f, 0.f, 0.f}, cs2[3] = {0.f, 0.f, 0.f};
    for (int mt = wave; mt < NTl; mt += 4) {
        f32x4 d[3];
        gemm_tile(shHf, bfr, mt, lane, d);
        if (half && mt == 5) {               // only ragged tile needs guards
            int grow0 = 192 + q * 4;
#pragma unroll
            for (int nt = 0; nt < 3; ++nt)
#pragma unroll
                for (int r = 0; r < 4; ++r)
                    if (grow0 + r < SS) {
                        float vv = d[nt][r] + basev[nt];
                        cs1[nt] += vv;
                        cs2[nt] += vv * vv;
                    }
        } else {
#pragma unroll
            for (int nt = 0; nt < 3; ++nt)
#pragma unroll
                for (int r = 0; r < 4; ++r) {
                    float vv = d[nt][r] + basev[nt];
                    cs1[nt] += vv;
                    cs2[nt] += vv * vv;
                }
        }
    }
#pragma unroll
    for (int nt = 0; nt < 3; ++nt) {
        cs1[nt] += __shfl_xor(cs1[nt], 16);
        cs1[nt] += __shfl_xor(cs1[nt], 32);
        cs2[nt] += __shfl_xor(cs2[nt], 16);
        cs2[nt] += __shfl_xor(cs2[nt], 32);
    }
    if (lane < 16) {
#pragma unroll
        for (int nt = 0; nt < 3; ++nt) {
            shP1[wave][nt * 16 + lane] = cs1[nt];
            shP2[wave][nt * 16 + lane] = cs2[nt];
        }
    }
    __syncthreads();
    if (RED) {
        if (t < HH)
            pstat[(size_t)bx * PSTRIDE + t] =
                shP1[0][t] + shP1[1][t] + shP1[2][t] + shP1[3][t];
        else if (t < 2 * HH) {
            int f = t - HH;
            pstat[(size_t)bx * PSTRIDE + t] =
                shP2[0][f] + shP2[1][f] + shP2[2][f] + shP2[3][f];
        }
    } else {
        if (t < HH) {
            atomicAdd(gsum + t, shP1[0][t] + shP1[1][t] + shP1[2][t] + shP1[3][t]);
            atomicAdd(gsum2 + t, shP2[0][t] + shP2[1][t] + shP2[2][t] + shP2[3][t]);
        }
    }
}

// ---------------------------------------------------------------------------
// Stats reduce (RED): block f reduces feature-f partials over 8192 blocks.
// ---------------------------------------------------------------------------
__global__ __launch_bounds__(256) void k_stats_red(const float* __restrict__ pstat,
                                                   const float* __restrict__ gamma,
                                                   const float* __restrict__ beta,
                                                   float* __restrict__ A,
                                                   float* __restrict__ Bc) {
    int f = blockIdx.x, t = threadIdx.x;
    if (f >= HH) {
        if (t == 0) { A[f] = 0.f; Bc[f] = 0.f; }
        return;
    }
    float s1 = 0.f, s2 = 0.f;
    for (int r = t; r < NPB; r += 256) {
        s1 += pstat[(size_t)r * PSTRIDE + f];
        s2 += pstat[(size_t)r * PSTRIDE + HH + f];
    }
#pragma unroll
    for (int off = 1; off < 64; off <<= 1) {
        s1 += __shfl_xor(s1, off);
        s2 += __shfl_xor(s2, off);
    }
    __shared__ float a1[4], a2[4];
    if ((t & 63) == 0) { a1[t >> 6] = s1; a2[t >> 6] = s2; }
    __syncthreads();
    if (t == 0) {
        s1 = a1[0] + a1[1] + a1[2] + a1[3];
        s2 = a2[0] + a2[1] + a2[2] + a2[3];
        float mu = s1 * (1.0f / NROWSF);
        float var = s2 * (1.0f / NROWSF) - mu * mu;
        float a = rsqrtf(var + 1e-5f) * gamma[f];
        A[f] = a;
        Bc[f] = beta[f] - mu * a;
    }
}

// Atomic-fallback stats
__global__ void k_stats(const float* __restrict__ gsum, const float* __restrict__ gsum2,
                        const float* __restrict__ gamma, const float* __restrict__ beta,
                        float* __restrict__ A, float* __restrict__ Bc) {
    int t = threadIdx.x;
    if (t < NP) {
        if (t < HH) {
            float mu = gsum[t] * (1.0f / NROWSF);
            float var = gsum2[t] * (1.0f / NROWSF) - mu * mu;
            float a = rsqrtf(var + 1e-5f) * gamma[t];
            A[t] = a;
            Bc[t] = beta[t] - mu * a;
        } else {
            A[t] = 0.f;
            Bc[t] = 0.f;
        }
    }
}

// ---------------------------------------------------------------------------
// Pass 2: h -> BN affine -> Dice -> output linear -> pooling (fp32 LDS)
// ---------------------------------------------------------------------------
template <bool WB>
__global__ __launch_bounds__(256, 4) void k_pass2(const float* __restrict__ hist,
                                                  const float* __restrict__ cand,
                                                  const float* __restrict__ W1,
                                                  const float* __restrict__ b1,
                                                  const unsigned short* __restrict__ WbG,
                                                  const float* __restrict__ baseG,
                                                  const float* __restrict__ Acoef,
                                                  const float* __restrict__ Bcoef,
                                                  const float* __restrict__ alpha,
                                                  const float* __restrict__ W2,
                                                  const float* __restrict__ b2,
                                                  float* __restrict__ out) {
    __shared__ __align__(16) float shHf[112 * DD];
    __shared__ __align__(16) unsigned short shWbT[NP * DD];
    __shared__ float shC[WB ? 1 : DD], shBase[NP];
    __shared__ float shBaseP[WB ? 1 : 4][NP];
    __shared__ float shW[112];
    __shared__ float shPool[4][DD];
    int bx = blockIdx.x, b = bx >> 1, half = bx & 1;
    int t = threadIdx.x, wave = t >> 6, lane = t & 63;
    int col = lane & 15, q = lane >> 4;

    prologue<WB>(b, half, t, hist, cand, W1, b1, WbG, baseG, shHf, shWbT, shC,
                 shBase, shBaseP);

    bf16x8 bfr[3][2];
    load_bfrags(shWbT, lane, bfr);
    float baseAB[3], Ar[3], W2r[3];
#pragma unroll
    for (int nt = 0; nt < 3; ++nt) {
        int c = nt * 16 + col;
        Ar[nt] = Acoef[c];
        baseAB[nt] = fmaf(shBase[c], Ar[nt], Bcoef[c]);  // fold base into affine
        W2r[nt] = (c < HH) ? W2[c] : 0.f;
    }
    float alv = alpha[0], one_m_alv = 1.0f - alv, b2v = b2[0];

    const int NTl = half ? 6 : 7;
    for (int mt = wave; mt < NTl; mt += 4) {
        f32x4 d[3];
        gemm_tile(shHf, bfr, mt, lane, d);
        float hp[3][4];
#pragma unroll
        for (int nt = 0; nt < 3; ++nt)
#pragma unroll
            for (int r = 0; r < 4; ++r)
                hp[nt][r] = fmaf(d[nt][r], Ar[nt], baseAB[nt]);
        float s1[4], s2[4], wsum[4];
#pragma unroll
        for (int r = 0; r < 4; ++r) {
            s1[r] = hp[0][r] + hp[1][r] + hp[2][r];
            s2[r] = hp[0][r] * hp[0][r] + hp[1][r] * hp[1][r] + hp[2][r] * hp[2][r];
            s1[r] += __shfl_xor(s1[r], 1);
            s1[r] += __shfl_xor(s1[r], 2);
            s1[r] += __shfl_xor(s1[r], 4);
            s1[r] += __shfl_xor(s1[r], 8);
            s2[r] += __shfl_xor(s2[r], 1);
            s2[r] += __shfl_xor(s2[r], 2);
            s2[r] += __shfl_xor(s2[r], 4);
            s2[r] += __shfl_xor(s2[r], 8);
        }
#pragma unroll
        for (int r = 0; r < 4; ++r) {
            float avg = s1[r] * (1.0f / (float)HH);
            float var = s2[r] * (1.0f / (float)HH) - avg * avg;
            float inv = rsqrtf(var + 1e-3f);
            float wv = 0.f;
#pragma unroll
            for (int nt = 0; nt < 3; ++nt) {
                float z = (hp[nt][r] - avg) * inv;
                float ps = 1.0f / (1.0f + __expf(-z));
                float f = fmaf(ps, one_m_alv, alv);      // ps + (1-ps)*alpha
                wv = fmaf(hp[nt][r] * f, W2r[nt], wv);
            }
            wsum[r] = wv;
            wsum[r] += __shfl_xor(wsum[r], 1);
            wsum[r] += __shfl_xor(wsum[r], 2);
            wsum[r] += __shfl_xor(wsum[r], 4);
            wsum[r] += __shfl_xor(wsum[r], 8);
        }
        if (col == 0) {                      // pad-row w's land in shW[88..95], unread
            float4 o = {wsum[0] + b2v, wsum[1] + b2v, wsum[2] + b2v, wsum[3] + b2v};
            *(float4*)&shW[mt * 16 + q * 4] = o;
        }
    }
    __syncthreads();
    // pooling from the fp32 LDS tile: out[b][d] += sum_s w[s]*hist[s][d]
    {
        const int nR = half ? 88 : 112;
        float p = 0.f;
        for (int s = wave; s < nR; s += 4)
            p = fmaf(shW[s], shHf[s * DD + lane], p);
        shPool[wave][lane] = p;
    }
    __syncthreads();
    if (t < DD)
        atomicAdd(out + b * DD + t,
                  shPool[0][t] + shPool[1][t] + shPool[2][t] + shPool[3][t]);
}

// ---------------------------------------------------------------------------
extern "C" void kernel_launch(void* const* d_in, const int* in_sizes, int n_in,
                              void* d_out, int out_size, void* d_ws, size_t ws_size,
                              hipStream_t stream) {
    const float* hist = (const float*)d_in[0];
    const float* cand = (const float*)d_in[1];
    const float* W1 = (const float*)d_in[2];
    const float* b1 = (const float*)d_in[3];
    const float* gamma = (const float*)d_in[4];
    const float* beta = (const float*)d_in[5];
    const float* alpha = (const float*)d_in[6];
    const float* W2 = (const float*)d_in[7];
    const float* b2 = (const float*)d_in[8];
    float* out = (float*)d_out;
    float* ws = (float*)d_ws;

    const size_t pstatF = (size_t)NPB * PSTRIDE;     // 655360 floats
    const size_t baseF = (size_t)BB * NP;            // 196608 floats
    const size_t wbBytes = (size_t)BB * NP * DD * 2; // 25.17 MB
    const size_t fullNeed = (pstatF + 2 * NP + baseF) * 4 + wbBytes;  // ~28.6 MB
    const size_t midNeed = (pstatF + 2 * NP) * 4;                     // ~2.63 MB

    hipMemsetAsync(out, 0, (size_t)out_size * sizeof(float), stream);
    if (ws_size >= fullNeed) {
        float* pstat = ws;
        float* A = pstat + pstatF;
        float* Bc = A + NP;
        float* baseG = Bc + NP;
        unsigned short* WbG = (unsigned short*)(baseG + baseF);
        k_wb<<<BB, 256, 0, stream>>>(cand, W1, b1, WbG, baseG);
        k_pass1<true, true><<<NPB, 256, 0, stream>>>(hist, cand, W1, b1, WbG, baseG,
                                                     pstat, nullptr, nullptr);
        k_stats_red<<<NP, 256, 0, stream>>>(pstat, gamma, beta, A, Bc);
        k_pass2<true><<<NPB, 256, 0, stream>>>(hist, cand, W1, b1, WbG, baseG, A, Bc,
                                               alpha, W2, b2, out);
    } else if (ws_size >= midNeed) {
        float* pstat = ws;
        float* A = pstat + pstatF;
        float* Bc = A + NP;
        k_pass1<false, true><<<NPB, 256, 0, stream>>>(hist, cand, W1, b1, nullptr,
                                                      nullptr, pstat, nullptr, nullptr);
        k_stats_red<<<NP, 256, 0, stream>>>(pstat, gamma, beta, A, Bc);
        k_pass2<false><<<NPB, 256, 0, stream>>>(hist, cand, W1, b1, nullptr, nullptr,
                                                A, Bc, alpha, W2, b2, out);
    } else {
        float* gsum = ws;
        float* gsum2 = ws + NP;
        float* A = ws + 2 * NP;
        float* Bc = ws + 3 * NP;
        hipMemsetAsync(gsum, 0, 2 * NP * sizeof(float), stream);
        k_pass1<false, false><<<NPB, 256, 0, stream>>>(hist, cand, W1, b1, nullptr,
                                                       nullptr, nullptr, gsum, gsum2);
        k_stats<<<1, 64, 0, stream>>>(gsum, gsum2, gamma, beta, A, Bc);
        k_pass2<false><<<NPB, 256, 0, stream>>>(hist, cand, W1, b1, nullptr, nullptr,
                                                A, Bc, alpha, W2, b2, out);
    }
}

// Round 5
// 418.470 us; speedup vs baseline: 1.0344x; 1.0344x over previous
//
#include <hip/hip_runtime.h>
#include <hip/hip_bf16.h>
#include <math.h>

// B=4096, S=200, D=64, H=36
#define BB 4096
#define SS 200
#define DD 64
#define HH 36
#define NP 48            // H padded to 3 n-tiles of 16
#define NTI 13           // m-tiles per b: 208 rows = 200 real + 8 zero pads
#define NROWSF (4096.0f * 200.0f)
#define PSTRIDE 80       // per-block partial-stat row stride (dwords)

typedef short bf16x8 __attribute__((ext_vector_type(8)));
typedef float f32x4 __attribute__((ext_vector_type(4)));

__device__ __forceinline__ unsigned short f2bf(float f) {
    union { float f; unsigned u; } v; v.f = f;
    unsigned r = v.u + 0x7FFFu + ((v.u >> 16) & 1u);   // RNE
    return (unsigned short)(r >> 16);
}
__device__ __forceinline__ unsigned f2bf2(float a, float b) {
    union { __hip_bfloat162 h; unsigned u; } v;
    v.h = __float22bfloat162_rn(float2{a, b});         // packed cvt on gfx950
    return v.u;
}

// Fire-and-forget global->LDS DMA, 16B/lane. LDS dest is linear per wave
// (uniform base + lane*16) -- required by HW (m104).
__device__ __forceinline__ void gl_lds16(const void* g, void* l) {
    __builtin_amdgcn_global_load_lds(
        (const __attribute__((address_space(1))) unsigned*)g,
        (__attribute__((address_space(3))) unsigned*)l, 16, 0, 0);
}

// ---------------------------------------------------------------------------
// k_wb: per-b folded weights/bias, computed ONCE.
// WbG[b][n][k] bf16 (n<36 real, else 0); baseG[b][0..47].
//   Wb[k][n] = W1b[k][n] - W1c[k][n] + c[k]*W1d[k][n]
//   base[n]  = b1[n] + sum_k c[k]*(W1a[k][n] + W1c[k][n])
// ---------------------------------------------------------------------------
__global__ __launch_bounds__(256) void k_wb(const float* __restrict__ cand,
                                            const float* __restrict__ W1,
                                            const float* __restrict__ b1,
                                            unsigned short* __restrict__ WbG,
                                            float* __restrict__ baseG) {
    int b = blockIdx.x, t = threadIdx.x;
    __shared__ float shC[DD];
    if (t < DD) shC[t] = cand[b * DD + t];
    __syncthreads();
    unsigned short* wb = WbG + (size_t)b * (NP * DD);
#pragma unroll
    for (int u = 0; u < 12; ++u) {              // 48*64/256
        int e = t + u * 256;
        int n = e >> 6, k = e & 63;
        float val = 0.f;
        if (n < HH)
            val = W1[(DD + k) * HH + n] - W1[(2 * DD + k) * HH + n] +
                  shC[k] * W1[(3 * DD + k) * HH + n];
        wb[e] = f2bf(val);
    }
    if (t < NP) {
        float v = 0.f;
        if (t < HH) {
            v = b1[t];
            for (int k = 0; k < DD; ++k)
                v += shC[k] * (W1[k * HH + t] + W1[(2 * DD + k) * HH + t]);
        }
        baseG[b * NP + t] = v;
    }
}

// ---------------------------------------------------------------------------
// Prologue (512 threads): stage ALL 200 rows of hist[b] (fp32, linear, 50 KB)
// + WbT (bf16, 6 KB) + base, zero 8 pad rows. WB=true: one DMA burst, one
// barrier. WB=false: register-staged fallback rebuilding Wb from W1.
// ---------------------------------------------------------------------------
template <bool WB>
__device__ __forceinline__ void prologue512(int b, int t,
                                            const float* __restrict__ hist,
                                            const float* __restrict__ cand,
                                            const float* __restrict__ W1,
                                            const float* __restrict__ b1,
                                            const unsigned short* __restrict__ WbG,
                                            const float* __restrict__ baseG,
                                            float* shHf, unsigned short* shWbT,
                                            float* shC, float* shBase,
                                            float (*shBaseP)[NP]) {
    const float* hsrc = hist + (size_t)b * SS * DD;
    if (WB) {
        const char* hb = (const char*)hsrc;
        char* lb = (char*)shHf;
        // hist: 51200 B = 6.25 rounds of 512 lanes x 16 B
#pragma unroll
        for (int j = 0; j < 6; ++j)
            gl_lds16(hb + (j * 512 + t) * 16, lb + (j * 512 + t) * 16);
        if (t < 128) gl_lds16(hb + (3072 + t) * 16, lb + (3072 + t) * 16);
        // WbT: 6144 B = 384 lane-slots
        const char* wbsrc = (const char*)(WbG + (size_t)b * (NP * DD));
        if (t < 384) gl_lds16(wbsrc + t * 16, (char*)shWbT + t * 16);
        if (t < NP) shBase[t] = baseG[b * NP + t];
        if (t < 128)                          // zero pad rows 200..207
            *(float4*)&shHf[SS * DD + t * 4] = float4{0.f, 0.f, 0.f, 0.f};
        __syncthreads();                      // drains vmcnt (DMA) + lgkm
    } else {
        if (t < DD) shC[t] = cand[b * DD + t];
        const float4* src = (const float4*)hsrc;
        float4 v[7];
#pragma unroll
        for (int u = 0; u < 6; ++u) v[u] = src[t + u * 512];
        if (t < 128) v[6] = src[t + 3072];
        if (t < 128)
            *(float4*)&shHf[SS * DD + t * 4] = float4{0.f, 0.f, 0.f, 0.f};
        __syncthreads();                      // shC visible
#pragma unroll
        for (int u = 0; u < 6; ++u) *(float4*)&shHf[(t + u * 512) * 4] = v[u];
        if (t < 128) *(float4*)&shHf[(t + 3072) * 4] = v[6];
        for (int e = t; e < NP * DD; e += 512) {
            int n = e >> 6, k = e & 63;
            float val = 0.f;
            if (n < HH)
                val = W1[(DD + k) * HH + n] - W1[(2 * DD + k) * HH + n] +
                      shC[k] * W1[(3 * DD + k) * HH + n];
            shWbT[n * DD + k] = f2bf(val);
        }
        if (t < 4 * NP) {
            int g = t / NP, j = t - g * NP;
            float p = 0.f;
            if (j < HH) {
#pragma unroll 4
                for (int k = 16 * g; k < 16 * g + 16; ++k)
                    p += shC[k] * (W1[k * HH + j] + W1[(2 * DD + k) * HH + j]);
            }
            shBaseP[g][j] = p;
        }
        __syncthreads();
        if (t < NP) {
            float val = (t < HH) ? b1[t] : 0.f;
            shBase[t] = val + shBaseP[0][t] + shBaseP[1][t] + shBaseP[2][t] +
                        shBaseP[3][t];
        }
        __syncthreads();
    }
}

__device__ __forceinline__ void load_bfrags(const unsigned short* shWbT, int lane,
                                            bf16x8 (&bfr)[3][2]) {
    int col = lane & 15, q = lane >> 4;
#pragma unroll
    for (int nt = 0; nt < 3; ++nt)
#pragma unroll
        for (int kt = 0; kt < 2; ++kt)
            bfr[nt][kt] = *(const bf16x8*)&shWbT[(nt * 16 + col) * DD + kt * 32 + q * 8];
}

// A-fragment: read 8 fp32 from linear LDS, pack to bf16 (RNE)
__device__ __forceinline__ bf16x8 load_afrag(const float* shHf, int m, int kt, int q) {
    const float* rp = shHf + m * DD + kt * 32 + q * 8;
    f32x4 x0 = *(const f32x4*)rp;
    f32x4 x1 = *(const f32x4*)(rp + 4);
    union { bf16x8 b8; unsigned u[4]; } a;
    a.u[0] = f2bf2(x0[0], x0[1]);
    a.u[1] = f2bf2(x0[2], x0[3]);
    a.u[2] = f2bf2(x1[0], x1[1]);
    a.u[3] = f2bf2(x1[2], x1[3]);
    return a.b8;
}

__device__ __forceinline__ void gemm_tile(const float* shHf,
                                          const bf16x8 (&bfr)[3][2], int mt, int lane,
                                          f32x4 (&d)[3]) {
    int m = mt * 16 + (lane & 15), q = lane >> 4;
    d[0] = f32x4{0.f, 0.f, 0.f, 0.f};
    d[1] = f32x4{0.f, 0.f, 0.f, 0.f};
    d[2] = f32x4{0.f, 0.f, 0.f, 0.f};
#pragma unroll
    for (int kt = 0; kt < 2; ++kt) {
        bf16x8 a = load_afrag(shHf, m, kt, q);
#pragma unroll
        for (int nt = 0; nt < 3; ++nt)
            d[nt] = __builtin_amdgcn_mfma_f32_16x16x32_bf16(a, bfr[nt][kt], d[nt], 0, 0, 0);
    }
}

// ---------------------------------------------------------------------------
// Pass 1: column sums of h and h^2 (BN batch statistics). One block per b.
// ---------------------------------------------------------------------------
template <bool WB, bool RED>
__global__ __launch_bounds__(512, 4) void k_pass1(const float* __restrict__ hist,
                                                  const float* __restrict__ cand,
                                                  const float* __restrict__ W1,
                                                  const float* __restrict__ b1,
                                                  const unsigned short* __restrict__ WbG,
                                                  const float* __restrict__ baseG,
                                                  float* __restrict__ pstat,
                                                  float* __restrict__ gsum,
                                                  float* __restrict__ gsum2) {
    __shared__ __align__(16) float shHf[(SS + 8) * DD];
    __shared__ __align__(16) unsigned short shWbT[NP * DD];
    __shared__ float shC[WB ? 1 : DD], shBase[NP];
    __shared__ float shBaseP[WB ? 1 : 4][NP];
    __shared__ float shP1[8][NP], shP2[8][NP];
    int b = blockIdx.x;
    int t = threadIdx.x, wave = t >> 6, lane = t & 63;
    int col = lane & 15, q = lane >> 4;

    prologue512<WB>(b, t, hist, cand, W1, b1, WbG, baseG, shHf, shWbT, shC,
                    shBase, shBaseP);

    bf16x8 bfr[3][2];
    load_bfrags(shWbT, lane, bfr);
    float basev[3];
#pragma unroll
    for (int nt = 0; nt < 3; ++nt) basev[nt] = shBase[nt * 16 + col];

    float cs1[3] = {0.f, 0.f, 0.f}, cs2[3] = {0.f, 0.f, 0.f};
    for (int mt = wave; mt < NTI; mt += 8) {
        f32x4 d[3];
        gemm_tile(shHf, bfr, mt, lane, d);
        if (mt == 12) {                      // ragged tile: rows 192..207
            int grow0 = 192 + q * 4;
#pragma unroll
            for (int nt = 0; nt < 3; ++nt)
#pragma unroll
                for (int r = 0; r < 4; ++r)
                    if (grow0 + r < SS) {
                        float vv = d[nt][r] + basev[nt];
                        cs1[nt] += vv;
                        cs2[nt] += vv * vv;
                    }
        } else {
#pragma unroll
            for (int nt = 0; nt < 3; ++nt)
#pragma unroll
                for (int r = 0; r < 4; ++r) {
                    float vv = d[nt][r] + basev[nt];
                    cs1[nt] += vv;
                    cs2[nt] += vv * vv;
                }
        }
    }
#pragma unroll
    for (int nt = 0; nt < 3; ++nt) {
        cs1[nt] += __shfl_xor(cs1[nt], 16);
        cs1[nt] += __shfl_xor(cs1[nt], 32);
        cs2[nt] += __shfl_xor(cs2[nt], 16);
        cs2[nt] += __shfl_xor(cs2[nt], 32);
    }
    if (lane < 16) {
#pragma unroll
        for (int nt = 0; nt < 3; ++nt) {
            shP1[wave][nt * 16 + lane] = cs1[nt];
            shP2[wave][nt * 16 + lane] = cs2[nt];
        }
    }
    __syncthreads();
    if (RED) {
        if (t < HH) {
            float s = 0.f;
#pragma unroll
            for (int w = 0; w < 8; ++w) s += shP1[w][t];
            pstat[(size_t)b * PSTRIDE + t] = s;
        } else if (t < 2 * HH) {
            int f = t - HH;
            float s = 0.f;
#pragma unroll
            for (int w = 0; w < 8; ++w) s += shP2[w][f];
            pstat[(size_t)b * PSTRIDE + t] = s;
        }
    } else {
        if (t < HH) {
            float s1 = 0.f, s2 = 0.f;
#pragma unroll
            for (int w = 0; w < 8; ++w) { s1 += shP1[w][t]; s2 += shP2[w][t]; }
            atomicAdd(gsum + t, s1);
            atomicAdd(gsum2 + t, s2);
        }
    }
}

// ---------------------------------------------------------------------------
// Stats reduce (RED): block f reduces feature-f partials over 4096 blocks.
// ---------------------------------------------------------------------------
__global__ __launch_bounds__(256) void k_stats_red(const float* __restrict__ pstat,
                                                   const float* __restrict__ gamma,
                                                   const float* __restrict__ beta,
                                                   float* __restrict__ A,
                                                   float* __restrict__ Bc) {
    int f = blockIdx.x, t = threadIdx.x;
    if (f >= HH) {
        if (t == 0) { A[f] = 0.f; Bc[f] = 0.f; }
        return;
    }
    float s1 = 0.f, s2 = 0.f;
    for (int r = t; r < BB; r += 256) {
        s1 += pstat[(size_t)r * PSTRIDE + f];
        s2 += pstat[(size_t)r * PSTRIDE + HH + f];
    }
#pragma unroll
    for (int off = 1; off < 64; off <<= 1) {
        s1 += __shfl_xor(s1, off);
        s2 += __shfl_xor(s2, off);
    }
    __shared__ float a1[4], a2[4];
    if ((t & 63) == 0) { a1[t >> 6] = s1; a2[t >> 6] = s2; }
    __syncthreads();
    if (t == 0) {
        s1 = a1[0] + a1[1] + a1[2] + a1[3];
        s2 = a2[0] + a2[1] + a2[2] + a2[3];
        float mu = s1 * (1.0f / NROWSF);
        float var = s2 * (1.0f / NROWSF) - mu * mu;
        float a = rsqrtf(var + 1e-5f) * gamma[f];
        A[f] = a;
        Bc[f] = beta[f] - mu * a;
    }
}

// Atomic-fallback stats
__global__ void k_stats(const float* __restrict__ gsum, const float* __restrict__ gsum2,
                        const float* __restrict__ gamma, const float* __restrict__ beta,
                        float* __restrict__ A, float* __restrict__ Bc) {
    int t = threadIdx.x;
    if (t < NP) {
        if (t < HH) {
            float mu = gsum[t] * (1.0f / NROWSF);
            float var = gsum2[t] * (1.0f / NROWSF) - mu * mu;
            float a = rsqrtf(var + 1e-5f) * gamma[t];
            A[t] = a;
            Bc[t] = beta[t] - mu * a;
        } else {
            A[t] = 0.f;
            Bc[t] = 0.f;
        }
    }
}

// ---------------------------------------------------------------------------
// Pass 2: h -> BN affine -> Dice -> output linear -> pooling. One block per b;
// out written by plain store (no atomics, no memset).
// ---------------------------------------------------------------------------
template <bool WB>
__global__ __launch_bounds__(512, 4) void k_pass2(const float* __restrict__ hist,
                                                  const float* __restrict__ cand,
                                                  const float* __restrict__ W1,
                                                  const float* __restrict__ b1,
                                                  const unsigned short* __restrict__ WbG,
                                                  const float* __restrict__ baseG,
                                                  const float* __restrict__ Acoef,
                                                  const float* __restrict__ Bcoef,
                                                  const float* __restrict__ alpha,
                                                  const float* __restrict__ W2,
                                                  const float* __restrict__ b2,
                                                  float* __restrict__ out) {
    __shared__ __align__(16) float shHf[(SS + 8) * DD];
    __shared__ __align__(16) unsigned short shWbT[NP * DD];
    __shared__ float shC[WB ? 1 : DD], shBase[NP];
    __shared__ float shBaseP[WB ? 1 : 4][NP];
    __shared__ float shW[(SS + 8)];
    __shared__ float shPool[8][DD];
    int b = blockIdx.x;
    int t = threadIdx.x, wave = t >> 6, lane = t & 63;
    int col = lane & 15, q = lane >> 4;

    prologue512<WB>(b, t, hist, cand, W1, b1, WbG, baseG, shHf, shWbT, shC,
                    shBase, shBaseP);

    bf16x8 bfr[3][2];
    load_bfrags(shWbT, lane, bfr);
    float baseAB[3], Ar[3], W2r[3];
#pragma unroll
    for (int nt = 0; nt < 3; ++nt) {
        int c = nt * 16 + col;
        Ar[nt] = Acoef[c];
        baseAB[nt] = fmaf(shBase[c], Ar[nt], Bcoef[c]);  // fold base into affine
        W2r[nt] = (c < HH) ? W2[c] : 0.f;
    }
    float alv = alpha[0], one_m_alv = 1.0f - alv, b2v = b2[0];

    for (int mt = wave; mt < NTI; mt += 8) {
        f32x4 d[3];
        gemm_tile(shHf, bfr, mt, lane, d);
        float hp[3][4];
#pragma unroll
        for (int nt = 0; nt < 3; ++nt)
#pragma unroll
            for (int r = 0; r < 4; ++r)
                hp[nt][r] = fmaf(d[nt][r], Ar[nt], baseAB[nt]);
        float s1[4], s2[4], wsum[4];
#pragma unroll
        for (int r = 0; r < 4; ++r) {
            s1[r] = hp[0][r] + hp[1][r] + hp[2][r];
            s2[r] = hp[0][r] * hp[0][r] + hp[1][r] * hp[1][r] + hp[2][r] * hp[2][r];
            s1[r] += __shfl_xor(s1[r], 1);
            s1[r] += __shfl_xor(s1[r], 2);
            s1[r] += __shfl_xor(s1[r], 4);
            s1[r] += __shfl_xor(s1[r], 8);
            s2[r] += __shfl_xor(s2[r], 1);
            s2[r] += __shfl_xor(s2[r], 2);
            s2[r] += __shfl_xor(s2[r], 4);
            s2[r] += __shfl_xor(s2[r], 8);
        }
#pragma unroll
        for (int r = 0; r < 4; ++r) {
            float avg = s1[r] * (1.0f / (float)HH);
            float var = s2[r] * (1.0f / (float)HH) - avg * avg;
            float inv = rsqrtf(var + 1e-3f);
            float wv = 0.f;
#pragma unroll
            for (int nt = 0; nt < 3; ++nt) {
                float z = (hp[nt][r] - avg) * inv;
                float ps = 1.0f / (1.0f + __expf(-z));
                float f = fmaf(ps, one_m_alv, alv);      // ps + (1-ps)*alpha
                wv = fmaf(hp[nt][r] * f, W2r[nt], wv);
            }
            wsum[r] = wv;
            wsum[r] += __shfl_xor(wsum[r], 1);
            wsum[r] += __shfl_xor(wsum[r], 2);
            wsum[r] += __shfl_xor(wsum[r], 4);
            wsum[r] += __shfl_xor(wsum[r], 8);
        }
        if (col == 0) {                      // pad-row w's land in shW[200..207], unread
            float4 o = {wsum[0] + b2v, wsum[1] + b2v, wsum[2] + b2v, wsum[3] + b2v};
            *(float4*)&shW[mt * 16 + q * 4] = o;
        }
    }
    __syncthreads();
    // pooling: out[b][d] = sum_s w[s]*hist[s][d], fp32 LDS, 8 waves x 25 rows
    {
        float p = 0.f;
        for (int s = wave; s < SS; s += 8)
            p = fmaf(shW[s], shHf[s * DD + lane], p);
        shPool[wave][lane] = p;
    }
    __syncthreads();
    if (t < DD) {
        float s = 0.f;
#pragma unroll
        for (int w = 0; w < 8; ++w) s += shPool[w][t];
        out[b * DD + t] = s;
    }
}

// ---------------------------------------------------------------------------
extern "C" void kernel_launch(void* const* d_in, const int* in_sizes, int n_in,
                              void* d_out, int out_size, void* d_ws, size_t ws_size,
                              hipStream_t stream) {
    const float* hist = (const float*)d_in[0];
    const float* cand = (const float*)d_in[1];
    const float* W1 = (const float*)d_in[2];
    const float* b1 = (const float*)d_in[3];
    const float* gamma = (const float*)d_in[4];
    const float* beta = (const float*)d_in[5];
    const float* alpha = (const float*)d_in[6];
    const float* W2 = (const float*)d_in[7];
    const float* b2 = (const float*)d_in[8];
    float* out = (float*)d_out;
    float* ws = (float*)d_ws;

    const size_t pstatF = (size_t)BB * PSTRIDE;      // 327680 floats
    const size_t baseF = (size_t)BB * NP;            // 196608 floats
    const size_t wbBytes = (size_t)BB * NP * DD * 2; // 25.17 MB
    const size_t fullNeed = (pstatF + 2 * NP + baseF) * 4 + wbBytes;
    const size_t midNeed = (pstatF + 2 * NP) * 4;

    if (ws_size >= fullNeed) {
        float* pstat = ws;
        float* A = pstat + pstatF;
        float* Bc = A + NP;
        float* baseG = Bc + NP;
        unsigned short* WbG = (unsigned short*)(baseG + baseF);
        k_wb<<<BB, 256, 0, stream>>>(cand, W1, b1, WbG, baseG);
        k_pass1<true, true><<<BB, 512, 0, stream>>>(hist, cand, W1, b1, WbG, baseG,
                                                    pstat, nullptr, nullptr);
        k_stats_red<<<NP, 256, 0, stream>>>(pstat, gamma, beta, A, Bc);
        k_pass2<true><<<BB, 512, 0, stream>>>(hist, cand, W1, b1, WbG, baseG, A, Bc,
                                              alpha, W2, b2, out);
    } else if (ws_size >= midNeed) {
        float* pstat = ws;
        float* A = pstat + pstatF;
        float* Bc = A + NP;
        k_pass1<false, true><<<BB, 512, 0, stream>>>(hist, cand, W1, b1, nullptr,
                                                     nullptr, pstat, nullptr, nullptr);
        k_stats_red<<<NP, 256, 0, stream>>>(pstat, gamma, beta, A, Bc);
        k_pass2<false><<<BB, 512, 0, stream>>>(hist, cand, W1, b1, nullptr, nullptr,
                                               A, Bc, alpha, W2, b2, out);
    } else {
        float* gsum = ws;
        float* gsum2 = ws + NP;
        float* A = ws + 2 * NP;
        float* Bc = ws + 3 * NP;
        hipMemsetAsync(gsum, 0, 2 * NP * sizeof(float), stream);
        k_pass1<false, false><<<BB, 512, 0, stream>>>(hist, cand, W1, b1, nullptr,
                                                      nullptr, nullptr, gsum, gsum2);
        k_stats<<<1, 64, 0, stream>>>(gsum, gsum2, gamma, beta, A, Bc);
        k_pass2<false><<<BB, 512, 0, stream>>>(hist, cand, W1, b1, nullptr, nullptr,
                                               A, Bc, alpha, W2, b2, out);
    }
}